// Round 1
// baseline (2613.629 us; speedup 1.0000x reference)
//
#include <hip/hip_runtime.h>
#include <hip/hip_bf16.h>
#include <cstdint>
#include <cstddef>

#define BATCH 2
#define NNODE 50000
#define NEDGE 150000
#define FDIM 256
#define MTOT (BATCH * NNODE)   // 100000 rows

typedef __attribute__((ext_vector_type(8))) __bf16 bf16x8;
typedef __attribute__((ext_vector_type(4))) float f32x4;

__device__ __forceinline__ ushort f32_to_bf16_rne(float x) {
    uint32_t u = __builtin_bit_cast(uint32_t, x);
    u = (u + 0x7fffu + ((u >> 16) & 1u)) >> 16;
    return (ushort)u;
}

__device__ __forceinline__ void split2(float x, ushort& h, ushort& l) {
    h = f32_to_bf16_rne(x);
    float hf = __builtin_bit_cast(float, ((uint32_t)h) << 16);
    l = f32_to_bf16_rne(x - hf);
}

// ---------------------------------------------------------------------------
// Prep: W1 (768x256) -> transposed bf16 hi/lo [256][768]; W2 (256x256) same.
// ---------------------------------------------------------------------------
__global__ __launch_bounds__(256)
void prep_kernel(const float* __restrict__ W1, const float* __restrict__ W2,
                 ushort* __restrict__ W1h, ushort* __restrict__ W1l,
                 ushort* __restrict__ W2h, ushort* __restrict__ W2l) {
    int idx = blockIdx.x * 256 + threadIdx.x;
    if (idx < 768 * 256) {
        int k = idx >> 8, n = idx & 255;
        ushort h, l;
        split2(W1[idx], h, l);
        W1h[n * 768 + k] = h;
        W1l[n * 768 + k] = l;
    }
    if (idx < 256 * 256) {
        int k = idx >> 8, n = idx & 255;
        ushort h, l;
        split2(W2[idx], h, l);
        W2h[n * 256 + k] = h;
        W2l[n * 256 + k] = l;
    }
}

// ---------------------------------------------------------------------------
// Aggregation: one wave (64 lanes x float4 = 256 floats) per edge.
// mi[b][ri] += e * X[b][ro];  mo[b][ro] += e * X[b][ri]
// ---------------------------------------------------------------------------
__global__ __launch_bounds__(256)
void agg_kernel(const float* __restrict__ X, const float* __restrict__ e,
                const int* __restrict__ ri, const int* __restrict__ ro,
                float* __restrict__ mi, float* __restrict__ mo) {
    int w = (int)((blockIdx.x * 256u + threadIdx.x) >> 6);
    int lane = threadIdx.x & 63;
    if (w >= BATCH * NEDGE) return;
    int b = w / NEDGE;
    float ew = e[w];
    int vri = ri[w];
    int vro = ro[w];
    size_t base = (size_t)b * NNODE;
    const float4* xo = (const float4*)(X + (base + vro) * FDIM);
    const float4* xi = (const float4*)(X + (base + vri) * FDIM);
    float4 a = xo[lane];
    float4 c = xi[lane];
    float* pmi = mi + (base + vri) * FDIM + lane * 4;
    float* pmo = mo + (base + vro) * FDIM + lane * 4;
    atomicAdd(pmi + 0, ew * a.x);
    atomicAdd(pmi + 1, ew * a.y);
    atomicAdd(pmi + 2, ew * a.z);
    atomicAdd(pmi + 3, ew * a.w);
    atomicAdd(pmo + 0, ew * c.x);
    atomicAdd(pmo + 1, ew * c.y);
    atomicAdd(pmo + 2, ew * c.z);
    atomicAdd(pmo + 3, ew * c.w);
}

// ---------------------------------------------------------------------------
// Split-bf16 GEMM.  C = tanh(A @ W + bias).
//   SECOND=false: A[r][k] = {mi,mo,X} (fp32), KTOT=768, output packed hi/lo uint32
//   SECOND=true : A = packed h (uint32 hi|lo<<16), KTOT=256, output fp32 -> d_out
// Tile 128x128, BK=32, 4 waves (each 64x64 = 4x4 frags of 16x16x32 MFMA).
// 3-MFMA split: ah*bh + al*bh + ah*bl  (error ~1e-4).
// ---------------------------------------------------------------------------
template<int KTOT, bool SECOND>
__global__ __launch_bounds__(256, 2)
void gemm_kernel(const float* __restrict__ A0, const float* __restrict__ A1,
                 const float* __restrict__ A2,
                 const ushort* __restrict__ Bhg, const ushort* __restrict__ Blg,
                 const float* __restrict__ bias,
                 uint32_t* __restrict__ hout, float* __restrict__ fout) {
    // stride 36 elements (72B): bank step 18 -> <=2-way conflicts (free)
    __shared__ ushort Ah[128][36], Al[128][36], Bh[128][36], Bl[128][36];

    int tid = threadIdx.x;
    int lane = tid & 63;
    int wid = tid >> 6;
    int wm = wid >> 1, wn = wid & 1;
    int r0 = blockIdx.x * 128;
    int c0 = blockIdx.y * 128;

    f32x4 acc[4][4];
    f32x4 zero4 = {0.f, 0.f, 0.f, 0.f};
#pragma unroll
    for (int m = 0; m < 4; ++m)
#pragma unroll
        for (int n = 0; n < 4; ++n) acc[m][n] = zero4;

    for (int k0 = 0; k0 < KTOT; k0 += 32) {
        // ---- stage A tile (128 rows x 32 k) ----
        {
            int c4 = (tid & 7) * 4;     // 0..28
            int rr = tid >> 3;          // 0..31
            if constexpr (!SECOND) {
                const float* src;
                int kb;
                if (k0 < 256)      { src = A0; kb = k0; }
                else if (k0 < 512) { src = A1; kb = k0 - 256; }
                else               { src = A2; kb = k0 - 512; }
#pragma unroll
                for (int it = 0; it < 4; ++it) {
                    int row = it * 32 + rr;
                    int rg = r0 + row;
                    float4 v = make_float4(0.f, 0.f, 0.f, 0.f);
                    if (rg < MTOT) v = *(const float4*)(src + (size_t)rg * 256 + kb + c4);
                    ushort h0, l0, h1, l1, h2, l2, h3, l3;
                    split2(v.x, h0, l0); split2(v.y, h1, l1);
                    split2(v.z, h2, l2); split2(v.w, h3, l3);
                    *(ushort4*)&Ah[row][c4] = make_ushort4(h0, h1, h2, h3);
                    *(ushort4*)&Al[row][c4] = make_ushort4(l0, l1, l2, l3);
                }
            } else {
                const uint32_t* src = (const uint32_t*)A0;
#pragma unroll
                for (int it = 0; it < 4; ++it) {
                    int row = it * 32 + rr;
                    int rg = r0 + row;
                    uint4 v = make_uint4(0u, 0u, 0u, 0u);
                    if (rg < MTOT) v = *(const uint4*)(src + (size_t)rg * 256 + k0 + c4);
                    *(ushort4*)&Ah[row][c4] = make_ushort4((ushort)v.x, (ushort)v.y,
                                                           (ushort)v.z, (ushort)v.w);
                    *(ushort4*)&Al[row][c4] = make_ushort4((ushort)(v.x >> 16), (ushort)(v.y >> 16),
                                                           (ushort)(v.z >> 16), (ushort)(v.w >> 16));
                }
            }
        }
        // ---- stage B tile (128 cols x 32 k) from pre-transposed bf16 ----
        {
            int i = tid & 127;
            int seg = (tid >> 7) * 16;  // 0 or 16
            const ushort* gh = Bhg + (size_t)(c0 + i) * KTOT + k0 + seg;
            const ushort* gl = Blg + (size_t)(c0 + i) * KTOT + k0 + seg;
#pragma unroll
            for (int j = 0; j < 2; ++j) {
                *(uint4*)&Bh[i][seg + j * 8] = *(const uint4*)(gh + j * 8);
                *(uint4*)&Bl[i][seg + j * 8] = *(const uint4*)(gl + j * 8);
            }
        }
        __syncthreads();

        // ---- MFMA ----
        {
            int ko = (lane >> 4) * 8;
            bf16x8 ah[4], al[4], bh[4], bl[4];
#pragma unroll
            for (int m = 0; m < 4; ++m) {
                int row = wm * 64 + m * 16 + (lane & 15);
                ah[m] = *(const bf16x8*)&Ah[row][ko];
                al[m] = *(const bf16x8*)&Al[row][ko];
            }
#pragma unroll
            for (int n = 0; n < 4; ++n) {
                int coln = wn * 64 + n * 16 + (lane & 15);
                bh[n] = *(const bf16x8*)&Bh[coln][ko];
                bl[n] = *(const bf16x8*)&Bl[coln][ko];
            }
#pragma unroll
            for (int m = 0; m < 4; ++m)
#pragma unroll
                for (int n = 0; n < 4; ++n) {
                    acc[m][n] = __builtin_amdgcn_mfma_f32_16x16x32_bf16(ah[m], bh[n], acc[m][n], 0, 0, 0);
                    acc[m][n] = __builtin_amdgcn_mfma_f32_16x16x32_bf16(al[m], bh[n], acc[m][n], 0, 0, 0);
                    acc[m][n] = __builtin_amdgcn_mfma_f32_16x16x32_bf16(ah[m], bl[n], acc[m][n], 0, 0, 0);
                }
        }
        __syncthreads();
    }

    // ---- epilogue: bias + tanh ----
#pragma unroll
    for (int m = 0; m < 4; ++m) {
        int rbase = r0 + wm * 64 + m * 16 + ((lane >> 4) * 4);
#pragma unroll
        for (int n = 0; n < 4; ++n) {
            int col = c0 + wn * 64 + n * 16 + (lane & 15);
            float bv = bias[col];
#pragma unroll
            for (int q = 0; q < 4; ++q) {
                int row = rbase + q;
                if (row < MTOT) {
                    float t = tanhf(acc[m][n][q] + bv);
                    if constexpr (!SECOND) {
                        ushort h, l;
                        split2(t, h, l);
                        hout[(size_t)row * 256 + col] = (uint32_t)h | ((uint32_t)l << 16);
                    } else {
                        fout[(size_t)row * 256 + col] = t;
                    }
                }
            }
        }
    }
}

// ---------------------------------------------------------------------------
extern "C" void kernel_launch(void* const* d_in, const int* in_sizes, int n_in,
                              void* d_out, int out_size, void* d_ws, size_t ws_size,
                              hipStream_t stream) {
    const float* X  = (const float*)d_in[0];
    const float* e  = (const float*)d_in[1];
    const int*   ri = (const int*)d_in[2];
    const int*   ro = (const int*)d_in[3];
    const float* W1 = (const float*)d_in[4];
    const float* b1 = (const float*)d_in[5];
    const float* W2 = (const float*)d_in[6];
    const float* b2 = (const float*)d_in[7];
    float* out = (float*)d_out;

    char* ws = (char*)d_ws;
    const size_t szMI = (size_t)MTOT * 256 * 4;          // 102,400,000 B
    float*    mi   = (float*)ws;
    float*    mo   = (float*)(ws + szMI);
    uint32_t* hbuf = (uint32_t*)(ws + 2 * szMI);
    ushort*   W1h  = (ushort*)(ws + 3 * szMI);
    ushort*   W1l  = W1h + 768 * 256;
    ushort*   W2h  = W1l + 768 * 256;
    ushort*   W2l  = W2h + 256 * 256;

    // zero the atomic accumulators (ws is poisoned before every call)
    hipMemsetAsync(ws, 0, 2 * szMI, stream);

    prep_kernel<<<768, 256, 0, stream>>>(W1, W2, W1h, W1l, W2h, W2l);

    agg_kernel<<<(BATCH * NEDGE) / 4, 256, 0, stream>>>(X, e, ri, ro, mi, mo);

    dim3 grid1((MTOT + 127) / 128, 2);
    gemm_kernel<768, false><<<grid1, 256, 0, stream>>>(
        mi, mo, X, W1h, W1l, b1, hbuf, nullptr);

    gemm_kernel<256, true><<<grid1, 256, 0, stream>>>(
        (const float*)hbuf, nullptr, nullptr, W2h, W2l, b2, nullptr, out);
}

// Round 2
// 827.148 us; speedup vs baseline: 3.1598x; 3.1598x over previous
//
#include <hip/hip_runtime.h>
#include <hip/hip_bf16.h>
#include <cstdint>
#include <cstddef>

#define BATCH 2
#define NNODE 50000
#define NEDGE 150000
#define FDIM 256
#define MTOT (BATCH * NNODE)        // 100000 rows
#define NSEG (2 * BATCH * NNODE)    // 200000 CSR rows (2 tables x B x N)
#define NEDG2 (2 * BATCH * NEDGE)   // 600000 payload slots
#define SCAN_NB 98                  // ceil(200000 / 2048)

typedef __attribute__((ext_vector_type(8))) __bf16 bf16x8;
typedef __attribute__((ext_vector_type(4))) float f32x4;

__device__ __forceinline__ ushort f32_to_bf16_rne(float x) {
    uint32_t u = __builtin_bit_cast(uint32_t, x);
    u = (u + 0x7fffu + ((u >> 16) & 1u)) >> 16;
    return (ushort)u;
}

__device__ __forceinline__ void split2(float x, ushort& h, ushort& l) {
    h = f32_to_bf16_rne(x);
    float hf = __builtin_bit_cast(float, ((uint32_t)h) << 16);
    l = f32_to_bf16_rne(x - hf);
}

// ---------------------------------------------------------------------------
// Prep: W1 (768x256) -> transposed bf16 hi/lo [256][768]; W2 (256x256) same.
// ---------------------------------------------------------------------------
__global__ __launch_bounds__(256)
void prep_kernel(const float* __restrict__ W1, const float* __restrict__ W2,
                 ushort* __restrict__ W1h, ushort* __restrict__ W1l,
                 ushort* __restrict__ W2h, ushort* __restrict__ W2l) {
    int idx = blockIdx.x * 256 + threadIdx.x;
    if (idx < 768 * 256) {
        int k = idx >> 8, n = idx & 255;
        ushort h, l;
        split2(W1[idx], h, l);
        W1h[n * 768 + k] = h;
        W1l[n * 768 + k] = l;
    }
    if (idx < 256 * 256) {
        int k = idx >> 8, n = idx & 255;
        ushort h, l;
        split2(W2[idx], h, l);
        W2h[n * 256 + k] = h;
        W2l[n * 256 + k] = l;
    }
}

// ---------------------------------------------------------------------------
// CSR build: histogram -> 3-phase exclusive scan -> fill.
// Table 0: key=ri, val=ro (produces mi). Table 1: key=ro, val=ri (mo).
// ---------------------------------------------------------------------------
__global__ __launch_bounds__(256)
void hist_kernel(const int* __restrict__ ri, const int* __restrict__ ro,
                 int* __restrict__ cnt) {
    int j = blockIdx.x * 256 + threadIdx.x;
    if (j >= BATCH * NEDGE) return;
    int b = j / NEDGE;
    atomicAdd(&cnt[(0 * BATCH + b) * NNODE + ri[j]], 1);
    atomicAdd(&cnt[(1 * BATCH + b) * NNODE + ro[j]], 1);
}

__global__ __launch_bounds__(256)
void scan1_kernel(const int* __restrict__ cnt, int* __restrict__ rs,
                  int* __restrict__ bsum) {
    __shared__ int s[256];
    int tid = threadIdx.x;
    int base = blockIdx.x * 2048 + tid * 8;
    int v[8];
    int loc = 0;
#pragma unroll
    for (int j = 0; j < 8; ++j) {
        int idx = base + j;
        int x = (idx < NSEG) ? cnt[idx] : 0;
        v[j] = x;
        loc += x;
    }
    s[tid] = loc;
    __syncthreads();
    for (int off = 1; off < 256; off <<= 1) {
        int t = (tid >= off) ? s[tid - off] : 0;
        __syncthreads();
        s[tid] += t;
        __syncthreads();
    }
    int run = (tid == 0) ? 0 : s[tid - 1];
#pragma unroll
    for (int j = 0; j < 8; ++j) {
        int idx = base + j;
        if (idx < NSEG) rs[idx] = run;
        run += v[j];
    }
    if (tid == 255) bsum[blockIdx.x] = s[255];
}

__global__ __launch_bounds__(128)
void scan2_kernel(int* __restrict__ bsum) {
    __shared__ int s[128];
    int tid = threadIdx.x;
    int x = (tid < SCAN_NB) ? bsum[tid] : 0;
    s[tid] = x;
    __syncthreads();
    for (int off = 1; off < 128; off <<= 1) {
        int t = (tid >= off) ? s[tid - off] : 0;
        __syncthreads();
        s[tid] += t;
        __syncthreads();
    }
    int ex = (tid == 0) ? 0 : s[tid - 1];
    if (tid < SCAN_NB) bsum[tid] = ex;
}

__global__ __launch_bounds__(256)
void scan3_kernel(int* __restrict__ rs, int* __restrict__ cur,
                  const int* __restrict__ bsum) {
    int base = blockIdx.x * 2048 + threadIdx.x * 8;
    int off = bsum[blockIdx.x];
#pragma unroll
    for (int j = 0; j < 8; ++j) {
        int idx = base + j;
        if (idx < NSEG) {
            int v = rs[idx] + off;
            rs[idx] = v;
            cur[idx] = v;
        }
    }
}

__global__ __launch_bounds__(256)
void fill_kernel(const int* __restrict__ ri, const int* __restrict__ ro,
                 const float* __restrict__ e, int* __restrict__ cur,
                 int* __restrict__ pidx, float* __restrict__ pw) {
    int j = blockIdx.x * 256 + threadIdx.x;
    if (j >= BATCH * NEDGE) return;
    int b = j / NEDGE;
    int vri = ri[j], vro = ro[j];
    float ew = e[j];
    int p0 = atomicAdd(&cur[(0 * BATCH + b) * NNODE + vri], 1);
    pidx[p0] = vro;
    pw[p0] = ew;
    int p1 = atomicAdd(&cur[(1 * BATCH + b) * NNODE + vro], 1);
    pidx[p1] = vri;
    pw[p1] = ew;
}

// ---------------------------------------------------------------------------
// Gather: one wave per CSR row (table,b,node). Each lane owns float4 of the
// 256-wide feature. acc = sum over edges of ew * X[b][src]. Single write.
// ---------------------------------------------------------------------------
__global__ __launch_bounds__(256)
void gather_kernel(const float* __restrict__ X, const int* __restrict__ rs,
                   const int* __restrict__ cnt, const int* __restrict__ pidx,
                   const float* __restrict__ pw,
                   float* __restrict__ mi, float* __restrict__ mo) {
    int gid = blockIdx.x * 256 + threadIdx.x;
    int w = gid >> 6;
    int lane = gid & 63;
    if (w >= NSEG) return;
    int t = w / (BATCH * NNODE);
    int r = w - t * (BATCH * NNODE);
    int b = r / NNODE;
    int start = rs[w];
    int c = cnt[w];
    const float* Xb = X + (size_t)b * NNODE * FDIM;
    float4 acc = make_float4(0.f, 0.f, 0.f, 0.f);
    for (int i = 0; i < c; ++i) {
        int v = pidx[start + i];
        float ww = pw[start + i];
        float4 xv = *(const float4*)(Xb + (size_t)v * FDIM + lane * 4);
        acc.x += ww * xv.x;
        acc.y += ww * xv.y;
        acc.z += ww * xv.z;
        acc.w += ww * xv.w;
    }
    float* dst = (t == 0 ? mi : mo) + (size_t)r * FDIM + lane * 4;
    *(float4*)dst = acc;
}

// ---------------------------------------------------------------------------
// Split-bf16 GEMM.  C = tanh(A @ W + bias).   (unchanged from round 1)
// ---------------------------------------------------------------------------
template<int KTOT, bool SECOND>
__global__ __launch_bounds__(256, 2)
void gemm_kernel(const float* __restrict__ A0, const float* __restrict__ A1,
                 const float* __restrict__ A2,
                 const ushort* __restrict__ Bhg, const ushort* __restrict__ Blg,
                 const float* __restrict__ bias,
                 uint32_t* __restrict__ hout, float* __restrict__ fout) {
    __shared__ ushort Ah[128][36], Al[128][36], Bh[128][36], Bl[128][36];

    int tid = threadIdx.x;
    int lane = tid & 63;
    int wid = tid >> 6;
    int wm = wid >> 1, wn = wid & 1;
    int r0 = blockIdx.x * 128;
    int c0 = blockIdx.y * 128;

    f32x4 acc[4][4];
    f32x4 zero4 = {0.f, 0.f, 0.f, 0.f};
#pragma unroll
    for (int m = 0; m < 4; ++m)
#pragma unroll
        for (int n = 0; n < 4; ++n) acc[m][n] = zero4;

    for (int k0 = 0; k0 < KTOT; k0 += 32) {
        {
            int c4 = (tid & 7) * 4;
            int rr = tid >> 3;
            if constexpr (!SECOND) {
                const float* src;
                int kb;
                if (k0 < 256)      { src = A0; kb = k0; }
                else if (k0 < 512) { src = A1; kb = k0 - 256; }
                else               { src = A2; kb = k0 - 512; }
#pragma unroll
                for (int it = 0; it < 4; ++it) {
                    int row = it * 32 + rr;
                    int rg = r0 + row;
                    float4 v = make_float4(0.f, 0.f, 0.f, 0.f);
                    if (rg < MTOT) v = *(const float4*)(src + (size_t)rg * 256 + kb + c4);
                    ushort h0, l0, h1, l1, h2, l2, h3, l3;
                    split2(v.x, h0, l0); split2(v.y, h1, l1);
                    split2(v.z, h2, l2); split2(v.w, h3, l3);
                    *(ushort4*)&Ah[row][c4] = make_ushort4(h0, h1, h2, h3);
                    *(ushort4*)&Al[row][c4] = make_ushort4(l0, l1, l2, l3);
                }
            } else {
                const uint32_t* src = (const uint32_t*)A0;
#pragma unroll
                for (int it = 0; it < 4; ++it) {
                    int row = it * 32 + rr;
                    int rg = r0 + row;
                    uint4 v = make_uint4(0u, 0u, 0u, 0u);
                    if (rg < MTOT) v = *(const uint4*)(src + (size_t)rg * 256 + k0 + c4);
                    *(ushort4*)&Ah[row][c4] = make_ushort4((ushort)v.x, (ushort)v.y,
                                                           (ushort)v.z, (ushort)v.w);
                    *(ushort4*)&Al[row][c4] = make_ushort4((ushort)(v.x >> 16), (ushort)(v.y >> 16),
                                                           (ushort)(v.z >> 16), (ushort)(v.w >> 16));
                }
            }
        }
        {
            int i = tid & 127;
            int seg = (tid >> 7) * 16;
            const ushort* gh = Bhg + (size_t)(c0 + i) * KTOT + k0 + seg;
            const ushort* gl = Blg + (size_t)(c0 + i) * KTOT + k0 + seg;
#pragma unroll
            for (int j = 0; j < 2; ++j) {
                *(uint4*)&Bh[i][seg + j * 8] = *(const uint4*)(gh + j * 8);
                *(uint4*)&Bl[i][seg + j * 8] = *(const uint4*)(gl + j * 8);
            }
        }
        __syncthreads();

        {
            int ko = (lane >> 4) * 8;
            bf16x8 ah[4], al[4], bh[4], bl[4];
#pragma unroll
            for (int m = 0; m < 4; ++m) {
                int row = wm * 64 + m * 16 + (lane & 15);
                ah[m] = *(const bf16x8*)&Ah[row][ko];
                al[m] = *(const bf16x8*)&Al[row][ko];
            }
#pragma unroll
            for (int n = 0; n < 4; ++n) {
                int coln = wn * 64 + n * 16 + (lane & 15);
                bh[n] = *(const bf16x8*)&Bh[coln][ko];
                bl[n] = *(const bf16x8*)&Bl[coln][ko];
            }
#pragma unroll
            for (int m = 0; m < 4; ++m)
#pragma unroll
                for (int n = 0; n < 4; ++n) {
                    acc[m][n] = __builtin_amdgcn_mfma_f32_16x16x32_bf16(ah[m], bh[n], acc[m][n], 0, 0, 0);
                    acc[m][n] = __builtin_amdgcn_mfma_f32_16x16x32_bf16(al[m], bh[n], acc[m][n], 0, 0, 0);
                    acc[m][n] = __builtin_amdgcn_mfma_f32_16x16x32_bf16(ah[m], bl[n], acc[m][n], 0, 0, 0);
                }
        }
        __syncthreads();
    }

#pragma unroll
    for (int m = 0; m < 4; ++m) {
        int rbase = r0 + wm * 64 + m * 16 + ((lane >> 4) * 4);
#pragma unroll
        for (int n = 0; n < 4; ++n) {
            int col = c0 + wn * 64 + n * 16 + (lane & 15);
            float bv = bias[col];
#pragma unroll
            for (int q = 0; q < 4; ++q) {
                int row = rbase + q;
                if (row < MTOT) {
                    float t = tanhf(acc[m][n][q] + bv);
                    if constexpr (!SECOND) {
                        ushort h, l;
                        split2(t, h, l);
                        hout[(size_t)row * 256 + col] = (uint32_t)h | ((uint32_t)l << 16);
                    } else {
                        fout[(size_t)row * 256 + col] = t;
                    }
                }
            }
        }
    }
}

// ---------------------------------------------------------------------------
extern "C" void kernel_launch(void* const* d_in, const int* in_sizes, int n_in,
                              void* d_out, int out_size, void* d_ws, size_t ws_size,
                              hipStream_t stream) {
    const float* X  = (const float*)d_in[0];
    const float* e  = (const float*)d_in[1];
    const int*   ri = (const int*)d_in[2];
    const int*   ro = (const int*)d_in[3];
    const float* W1 = (const float*)d_in[4];
    const float* b1 = (const float*)d_in[5];
    const float* W2 = (const float*)d_in[6];
    const float* b2 = (const float*)d_in[7];
    float* out = (float*)d_out;

    char* ws = (char*)d_ws;
    const size_t szMI = (size_t)MTOT * 256 * 4;          // 102,400,000 B
    float*    mi   = (float*)ws;
    float*    mo   = (float*)(ws + szMI);
    char*     hreg = ws + 2 * szMI;                      // hbuf region, aliased by CSR temps
    uint32_t* hbuf = (uint32_t*)hreg;
    ushort*   W1h  = (ushort*)(ws + 3 * szMI);
    ushort*   W1l  = W1h + 768 * 256;
    ushort*   W2h  = W1l + 768 * 256;
    ushort*   W2l  = W2h + 256 * 256;

    // CSR temps live inside the hbuf region (dead before gemm1 writes hbuf).
    int*   cnt  = (int*)(hreg);                          // 800,000 B
    int*   rs   = (int*)(hreg + 800000);                 // 800,000 B
    int*   cur  = (int*)(hreg + 1600000);                // 800,000 B
    int*   bsum = (int*)(hreg + 2400000);                // 4,096 B
    int*   pidx = (int*)(hreg + 2404096);                // 2,400,000 B
    float* pw   = (float*)(hreg + 4804096);              // 2,400,000 B

    hipMemsetAsync(cnt, 0, (size_t)NSEG * 4, stream);

    prep_kernel<<<768, 256, 0, stream>>>(W1, W2, W1h, W1l, W2h, W2l);

    hist_kernel<<<(BATCH * NEDGE + 255) / 256, 256, 0, stream>>>(ri, ro, cnt);
    scan1_kernel<<<SCAN_NB, 256, 0, stream>>>(cnt, rs, bsum);
    scan2_kernel<<<1, 128, 0, stream>>>(bsum);
    scan3_kernel<<<SCAN_NB, 256, 0, stream>>>(rs, cur, bsum);
    fill_kernel<<<(BATCH * NEDGE + 255) / 256, 256, 0, stream>>>(ri, ro, e, cur, pidx, pw);

    gather_kernel<<<NSEG / 4, 256, 0, stream>>>(X, rs, cnt, pidx, pw, mi, mo);

    dim3 grid1((MTOT + 127) / 128, 2);
    gemm_kernel<768, false><<<grid1, 256, 0, stream>>>(
        mi, mo, X, W1h, W1l, b1, hbuf, nullptr);

    gemm_kernel<256, true><<<grid1, 256, 0, stream>>>(
        (const float*)hbuf, nullptr, nullptr, W2h, W2l, b2, nullptr, out);
}

// Round 3
// 676.300 us; speedup vs baseline: 3.8646x; 1.2230x over previous
//
#include <hip/hip_runtime.h>
#include <hip/hip_bf16.h>
#include <cstdint>
#include <cstddef>

#define BATCH 2
#define NNODE 50000
#define NEDGE 150000
#define FDIM 256
#define MTOT (BATCH * NNODE)        // 100000 rows
#define NSEG (2 * BATCH * NNODE)    // 200000 CSR rows
#define SCAN_NB 98                  // ceil(200000 / 2048)

typedef __attribute__((ext_vector_type(8))) __bf16 bf16x8;
typedef __attribute__((ext_vector_type(8))) ushort u16x8;
typedef __attribute__((ext_vector_type(4))) float f32x4;
typedef __attribute__((ext_vector_type(4))) uint32_t u32x4;

typedef const __attribute__((address_space(1))) uint32_t* gptr_t;
typedef __attribute__((address_space(3))) uint32_t* lptr_t;

__device__ __forceinline__ ushort f32_to_bf16_rne(float x) {
    uint32_t u = __builtin_bit_cast(uint32_t, x);
    u = (u + 0x7fffu + ((u >> 16) & 1u)) >> 16;
    return (ushort)u;
}

__device__ __forceinline__ void split2(float x, ushort& h, ushort& l) {
    h = f32_to_bf16_rne(x);
    float hf = __builtin_bit_cast(float, ((uint32_t)h) << 16);
    l = f32_to_bf16_rne(x - hf);
}

// ---------------------------------------------------------------------------
// Prep: build swizzled B LDS-images.
// img[blk][c][s][j] (blk = kb*2+cb, c=0..127, s=0..3, j=0..7 ushorts), where
// content at slot s = W[k = kb*32 + (s ^ ((c>>1)&3))*8 + j][col = cb*128+c].
// W1: 24 kb-blocks; W2: 8 kb-blocks.
// ---------------------------------------------------------------------------
__global__ __launch_bounds__(256)
void prep_kernel(const float* __restrict__ W1, const float* __restrict__ W2,
                 ushort* __restrict__ i1h, ushort* __restrict__ i1l,
                 ushort* __restrict__ i2h, ushort* __restrict__ i2l) {
    int idx = blockIdx.x * 256 + threadIdx.x;
    // W1: (kb, col, s): 24*256*4 = 24576 threads
    if (idx < 24576) {
        int kb = idx >> 10;
        int col = (idx >> 2) & 255;
        int s = idx & 3;
        int cb = col >> 7, c = col & 127;
        int sw = s ^ ((c >> 1) & 3);
        ushort hs[8], ls[8];
#pragma unroll
        for (int j = 0; j < 8; ++j) {
            int k = kb * 32 + sw * 8 + j;
            split2(W1[(size_t)k * 256 + col], hs[j], ls[j]);
        }
        size_t off = ((size_t)(kb * 2 + cb) * 128 + c) * 32 + s * 8;
#pragma unroll
        for (int j = 0; j < 8; ++j) { i1h[off + j] = hs[j]; i1l[off + j] = ls[j]; }
    }
    // W2: (kb, col, s): 8*256*4 = 8192 threads
    if (idx < 8192) {
        int kb = idx >> 10;
        int col = (idx >> 2) & 255;
        int s = idx & 3;
        int cb = col >> 7, c = col & 127;
        int sw = s ^ ((c >> 1) & 3);
        ushort hs[8], ls[8];
#pragma unroll
        for (int j = 0; j < 8; ++j) {
            int k = kb * 32 + sw * 8 + j;
            split2(W2[(size_t)k * 256 + col], hs[j], ls[j]);
        }
        size_t off = ((size_t)(kb * 2 + cb) * 128 + c) * 32 + s * 8;
#pragma unroll
        for (int j = 0; j < 8; ++j) { i2h[off + j] = hs[j]; i2l[off + j] = ls[j]; }
    }
}

// ---------------------------------------------------------------------------
// CSR build (unchanged)
// ---------------------------------------------------------------------------
__global__ __launch_bounds__(256)
void hist_kernel(const int* __restrict__ ri, const int* __restrict__ ro,
                 int* __restrict__ cnt) {
    int j = blockIdx.x * 256 + threadIdx.x;
    if (j >= BATCH * NEDGE) return;
    int b = j / NEDGE;
    atomicAdd(&cnt[(0 * BATCH + b) * NNODE + ri[j]], 1);
    atomicAdd(&cnt[(1 * BATCH + b) * NNODE + ro[j]], 1);
}

__global__ __launch_bounds__(256)
void scan1_kernel(const int* __restrict__ cnt, int* __restrict__ rs,
                  int* __restrict__ bsum) {
    __shared__ int s[256];
    int tid = threadIdx.x;
    int base = blockIdx.x * 2048 + tid * 8;
    int v[8];
    int loc = 0;
#pragma unroll
    for (int j = 0; j < 8; ++j) {
        int idx = base + j;
        int x = (idx < NSEG) ? cnt[idx] : 0;
        v[j] = x;
        loc += x;
    }
    s[tid] = loc;
    __syncthreads();
    for (int off = 1; off < 256; off <<= 1) {
        int t = (tid >= off) ? s[tid - off] : 0;
        __syncthreads();
        s[tid] += t;
        __syncthreads();
    }
    int run = (tid == 0) ? 0 : s[tid - 1];
#pragma unroll
    for (int j = 0; j < 8; ++j) {
        int idx = base + j;
        if (idx < NSEG) rs[idx] = run;
        run += v[j];
    }
    if (tid == 255) bsum[blockIdx.x] = s[255];
}

__global__ __launch_bounds__(128)
void scan2_kernel(int* __restrict__ bsum) {
    __shared__ int s[128];
    int tid = threadIdx.x;
    int x = (tid < SCAN_NB) ? bsum[tid] : 0;
    s[tid] = x;
    __syncthreads();
    for (int off = 1; off < 128; off <<= 1) {
        int t = (tid >= off) ? s[tid - off] : 0;
        __syncthreads();
        s[tid] += t;
        __syncthreads();
    }
    int ex = (tid == 0) ? 0 : s[tid - 1];
    if (tid < SCAN_NB) bsum[tid] = ex;
}

__global__ __launch_bounds__(256)
void scan3_kernel(int* __restrict__ rs, int* __restrict__ cur,
                  const int* __restrict__ bsum) {
    int base = blockIdx.x * 2048 + threadIdx.x * 8;
    int off = bsum[blockIdx.x];
#pragma unroll
    for (int j = 0; j < 8; ++j) {
        int idx = base + j;
        if (idx < NSEG) {
            int v = rs[idx] + off;
            rs[idx] = v;
            cur[idx] = v;
        }
    }
}

__global__ __launch_bounds__(256)
void fill_kernel(const int* __restrict__ ri, const int* __restrict__ ro,
                 const float* __restrict__ e, int* __restrict__ cur,
                 int* __restrict__ pidx, float* __restrict__ pw) {
    int j = blockIdx.x * 256 + threadIdx.x;
    if (j >= BATCH * NEDGE) return;
    int b = j / NEDGE;
    int vri = ri[j], vro = ro[j];
    float ew = e[j];
    int p0 = atomicAdd(&cur[(0 * BATCH + b) * NNODE + vri], 1);
    pidx[p0] = vro;
    pw[p0] = ew;
    int p1 = atomicAdd(&cur[(1 * BATCH + b) * NNODE + vro], 1);
    pidx[p1] = vri;
    pw[p1] = ew;
}

// ---------------------------------------------------------------------------
// Gather: one wave per CSR row; 2-edge unroll for load-level parallelism.
// ---------------------------------------------------------------------------
__global__ __launch_bounds__(256)
void gather_kernel(const float* __restrict__ X, const int* __restrict__ rs,
                   const int* __restrict__ cnt, const int* __restrict__ pidx,
                   const float* __restrict__ pw,
                   float* __restrict__ mi, float* __restrict__ mo) {
    int gid = blockIdx.x * 256 + threadIdx.x;
    int w = gid >> 6;
    int lane = gid & 63;
    if (w >= NSEG) return;
    int t = w / (BATCH * NNODE);
    int r = w - t * (BATCH * NNODE);
    int b = r / NNODE;
    int start = rs[w];
    int c = cnt[w];
    int end = start + c;
    const float* Xb = X + (size_t)b * NNODE * FDIM + lane * 4;
    float4 acc = make_float4(0.f, 0.f, 0.f, 0.f);
    int i = start;
    for (; i + 1 < end; i += 2) {
        int v0 = pidx[i], v1 = pidx[i + 1];
        float w0 = pw[i], w1 = pw[i + 1];
        float4 x0 = *(const float4*)(Xb + (size_t)v0 * FDIM);
        float4 x1 = *(const float4*)(Xb + (size_t)v1 * FDIM);
        acc.x += w0 * x0.x + w1 * x1.x;
        acc.y += w0 * x0.y + w1 * x1.y;
        acc.z += w0 * x0.z + w1 * x1.z;
        acc.w += w0 * x0.w + w1 * x1.w;
    }
    if (i < end) {
        int v0 = pidx[i];
        float w0 = pw[i];
        float4 x0 = *(const float4*)(Xb + (size_t)v0 * FDIM);
        acc.x += w0 * x0.x;
        acc.y += w0 * x0.y;
        acc.z += w0 * x0.z;
        acc.w += w0 * x0.w;
    }
    float* dst = (t == 0 ? mi : mo) + (size_t)r * FDIM + lane * 4;
    *(float4*)dst = acc;
}

// ---------------------------------------------------------------------------
// 2-phase pipelined split-bf16 GEMM.  C = tanh(A @ W + bias).
// AMODE 0: A = {mi,mo,X} fp32 (NT=24), split2 in-register, out packed u32.
// AMODE 1: A = hbuf packed u32 (NT=8), unpack in-register, out fp32.
// LDS 64KB: A dbuf 2x16KB (fp32/u32, 128B rows, slot-XOR swizzle),
//           B dbuf 2x(8KB h + 8KB l) streamed from prebuilt swizzled images.
// One vmcnt(0) + one s_barrier per K-step; next tile in flight during MFMA.
// ---------------------------------------------------------------------------
template<int NT, int AMODE>
__global__ __launch_bounds__(256, 2)
void gemm_kernel(const float* __restrict__ A0, const float* __restrict__ A1,
                 const float* __restrict__ A2,
                 const ushort* __restrict__ Bh_img, const ushort* __restrict__ Bl_img,
                 const float* __restrict__ bias,
                 uint32_t* __restrict__ hout, float* __restrict__ fout) {
    __shared__ char smem[65536];

    int tid = threadIdx.x;
    int lane = tid & 63;
    int w = tid >> 6;
    int wm = w >> 1, wn = w & 1;
    int r0 = blockIdx.x * 128;
    int cb = blockIdx.y;
    int c0 = cb * 128;

    f32x4 acc[4][4];
    f32x4 zero4 = {0.f, 0.f, 0.f, 0.f};
#pragma unroll
    for (int m = 0; m < 4; ++m)
#pragma unroll
        for (int n = 0; n < 4; ++n) acc[m][n] = zero4;

    auto stage = [&](int buf, int t) {
        // ---- A: 16KB (128 rows x 128B), 4 insts/wave, source slot-swizzled
        const char* asrc;
        int kb;
        if constexpr (AMODE == 0) {
            if (t < 8)       { asrc = (const char*)A0; kb = t * 128; }
            else if (t < 16) { asrc = (const char*)A1; kb = (t - 8) * 128; }
            else             { asrc = (const char*)A2; kb = (t - 16) * 128; }
        } else {
            asrc = (const char*)A0; kb = t * 128;
        }
        char* abase = smem + buf * 16384;
#pragma unroll
        for (int i = 0; i < 4; ++i) {
            int inst = w * 4 + i;
            int row = inst * 8 + (lane >> 3);
            int rowg = r0 + row;
            if (rowg > MTOT - 1) rowg = MTOT - 1;
            int slot = (lane & 7) ^ (row & 7);
            const char* g = asrc + (size_t)rowg * 1024 + kb + slot * 16;
            __builtin_amdgcn_global_load_lds((gptr_t)g, (lptr_t)(abase + inst * 1024), 16, 0, 0);
        }
        // ---- B: 8KB h + 8KB l, streamed from prebuilt image, 2+2 insts/wave
        int blk = t * 2 + cb;
        const ushort* sh = Bh_img + (size_t)blk * 4096;
        const ushort* sl = Bl_img + (size_t)blk * 4096;
        char* bhbase = smem + 32768 + buf * 16384;
        char* blbase = bhbase + 8192;
#pragma unroll
        for (int j = 0; j < 2; ++j) {
            int inst = w * 2 + j;
            __builtin_amdgcn_global_load_lds((gptr_t)(sh + inst * 512 + lane * 8),
                                             (lptr_t)(bhbase + inst * 1024), 16, 0, 0);
            __builtin_amdgcn_global_load_lds((gptr_t)(sl + inst * 512 + lane * 8),
                                             (lptr_t)(blbase + inst * 1024), 16, 0, 0);
        }
    };

    stage(0, 0);
    asm volatile("s_waitcnt vmcnt(0)" ::: "memory");
    __builtin_amdgcn_s_barrier();

    int cur = 0;
    for (int t = 0; t < NT; ++t) {
        if (t + 1 < NT) stage(cur ^ 1, t + 1);

        char* abase = smem + cur * 16384;
        char* bhbase = smem + 32768 + cur * 16384;
        char* blbase = bhbase + 8192;

        bf16x8 ah[4], al[4], bh[4], bl[4];
        int q0 = (lane >> 4) * 2;
#pragma unroll
        for (int m = 0; m < 4; ++m) {
            int row = wm * 64 + m * 16 + (lane & 15);
            const char* rp = abase + row * 128;
            if constexpr (AMODE == 0) {
                f32x4 lo = *(const f32x4*)(rp + ((q0) ^ (row & 7)) * 16);
                f32x4 hi = *(const f32x4*)(rp + ((q0 + 1) ^ (row & 7)) * 16);
                float v[8] = {lo[0], lo[1], lo[2], lo[3], hi[0], hi[1], hi[2], hi[3]};
                u16x8 hv, lv;
#pragma unroll
                for (int j = 0; j < 8; ++j) {
                    ushort hh, ll;
                    split2(v[j], hh, ll);
                    hv[j] = hh;
                    lv[j] = ll;
                }
                ah[m] = __builtin_bit_cast(bf16x8, hv);
                al[m] = __builtin_bit_cast(bf16x8, lv);
            } else {
                u32x4 lo = *(const u32x4*)(rp + ((q0) ^ (row & 7)) * 16);
                u32x4 hi = *(const u32x4*)(rp + ((q0 + 1) ^ (row & 7)) * 16);
                u16x8 hv, lv;
#pragma unroll
                for (int j = 0; j < 4; ++j) {
                    hv[j] = (ushort)lo[j];
                    lv[j] = (ushort)(lo[j] >> 16);
                    hv[j + 4] = (ushort)hi[j];
                    lv[j + 4] = (ushort)(hi[j] >> 16);
                }
                ah[m] = __builtin_bit_cast(bf16x8, hv);
                al[m] = __builtin_bit_cast(bf16x8, lv);
            }
        }
        int ks = lane >> 4;
#pragma unroll
        for (int n = 0; n < 4; ++n) {
            int c = wn * 64 + n * 16 + (lane & 15);
            int so = (ks ^ ((c >> 1) & 3)) * 16;
            bh[n] = *(const bf16x8*)(bhbase + c * 64 + so);
            bl[n] = *(const bf16x8*)(blbase + c * 64 + so);
        }
#pragma unroll
        for (int m = 0; m < 4; ++m)
#pragma unroll
            for (int n = 0; n < 4; ++n) {
                acc[m][n] = __builtin_amdgcn_mfma_f32_16x16x32_bf16(ah[m], bh[n], acc[m][n], 0, 0, 0);
                acc[m][n] = __builtin_amdgcn_mfma_f32_16x16x32_bf16(al[m], bh[n], acc[m][n], 0, 0, 0);
                acc[m][n] = __builtin_amdgcn_mfma_f32_16x16x32_bf16(ah[m], bl[n], acc[m][n], 0, 0, 0);
            }

        asm volatile("s_waitcnt vmcnt(0)" ::: "memory");
        __builtin_amdgcn_s_barrier();
        cur ^= 1;
    }

    // ---- epilogue: bias + tanh ----
#pragma unroll
    for (int m = 0; m < 4; ++m) {
        int rbase = r0 + wm * 64 + m * 16 + ((lane >> 4) * 4);
#pragma unroll
        for (int n = 0; n < 4; ++n) {
            int col = c0 + wn * 64 + n * 16 + (lane & 15);
            float bv = bias[col];
#pragma unroll
            for (int q = 0; q < 4; ++q) {
                int row = rbase + q;
                if (row < MTOT) {
                    float tv = tanhf(acc[m][n][q] + bv);
                    if constexpr (AMODE == 0) {
                        ushort h, l;
                        split2(tv, h, l);
                        hout[(size_t)row * 256 + col] = (uint32_t)h | ((uint32_t)l << 16);
                    } else {
                        fout[(size_t)row * 256 + col] = tv;
                    }
                }
            }
        }
    }
}

// ---------------------------------------------------------------------------
extern "C" void kernel_launch(void* const* d_in, const int* in_sizes, int n_in,
                              void* d_out, int out_size, void* d_ws, size_t ws_size,
                              hipStream_t stream) {
    const float* X  = (const float*)d_in[0];
    const float* e  = (const float*)d_in[1];
    const int*   ri = (const int*)d_in[2];
    const int*   ro = (const int*)d_in[3];
    const float* W1 = (const float*)d_in[4];
    const float* b1 = (const float*)d_in[5];
    const float* W2 = (const float*)d_in[6];
    const float* b2 = (const float*)d_in[7];
    float* out = (float*)d_out;

    char* ws = (char*)d_ws;
    const size_t szMI = (size_t)MTOT * 256 * 4;          // 102,400,000 B
    float*    mi   = (float*)ws;
    float*    mo   = (float*)(ws + szMI);
    char*     hreg = ws + 2 * szMI;                      // hbuf region (CSR temps alias)
    uint32_t* hbuf = (uint32_t*)hreg;
    ushort*   i1h  = (ushort*)(ws + 3 * szMI);           // 24*2*4096 = 196608 ushorts
    ushort*   i1l  = i1h + 196608;
    ushort*   i2h  = i1l + 196608;                       // 8*2*4096 = 65536 ushorts
    ushort*   i2l  = i2h + 65536;

    // CSR temps inside hbuf region (dead before gemm1 writes hbuf)
    int*   cnt  = (int*)(hreg);
    int*   rs   = (int*)(hreg + 800000);
    int*   cur  = (int*)(hreg + 1600000);
    int*   bsum = (int*)(hreg + 2400000);
    int*   pidx = (int*)(hreg + 2404096);
    float* pw   = (float*)(hreg + 4804096);

    hipMemsetAsync(cnt, 0, (size_t)NSEG * 4, stream);

    prep_kernel<<<96, 256, 0, stream>>>(W1, W2, i1h, i1l, i2h, i2l);

    hist_kernel<<<(BATCH * NEDGE + 255) / 256, 256, 0, stream>>>(ri, ro, cnt);
    scan1_kernel<<<SCAN_NB, 256, 0, stream>>>(cnt, rs, bsum);
    scan2_kernel<<<1, 128, 0, stream>>>(bsum);
    scan3_kernel<<<SCAN_NB, 256, 0, stream>>>(rs, cur, bsum);
    fill_kernel<<<(BATCH * NEDGE + 255) / 256, 256, 0, stream>>>(ri, ro, e, cur, pidx, pw);

    gather_kernel<<<NSEG / 4, 256, 0, stream>>>(X, rs, cnt, pidx, pw, mi, mo);

    dim3 grid1((MTOT + 127) / 128, 2);
    gemm_kernel<24, 0><<<grid1, 256, 0, stream>>>(
        mi, mo, X, i1h, i1l, b1, hbuf, nullptr);

    gemm_kernel<8, 1><<<grid1, 256, 0, stream>>>(
        (const float*)hbuf, nullptr, nullptr, i2h, i2l, b2, nullptr, out);
}